// Round 6
// baseline (311.658 us; speedup 1.0000x reference)
//
#include <hip/hip_runtime.h>
#include <hip/hip_bf16.h>
#include <cstdint>

#define T_TOKENS 8192
#define DIM 1024
#define NEXP 8
#define DFFH 1024      // DFF/2
#define ROWCAP 17408   // >= 2*T + 8*127, rounded
#define NCHUNK 16      // scatter chunks (512 tokens each)

typedef __attribute__((ext_vector_type(8))) short bf16x8;
typedef __attribute__((ext_vector_type(4))) float f32x4;

__device__ __forceinline__ ushort f2bf(float f) {
  uint32_t u = __float_as_uint(f);
  uint32_t r = (u + 0x7fffu + ((u >> 16) & 1u)) >> 16;
  return (ushort)r;
}
__device__ __forceinline__ float bf2f(ushort u) {
  return __uint_as_float(((uint32_t)u) << 16);
}

__device__ __forceinline__ void async16(const void* g, const void* l) {
  __builtin_amdgcn_global_load_lds(
      (const __attribute__((address_space(1))) void*)(uintptr_t)g,
      (__attribute__((address_space(3))) void*)(uintptr_t)l, 16, 0, 0);
}

// ---------------- cast fp32 -> bf16 for x, w1, w2 ----------------
__global__ __launch_bounds__(256) void cast_kernel(
    const float4* __restrict__ x, const float4* __restrict__ w1,
    const float4* __restrict__ w2, ushort* __restrict__ xb,
    ushort* __restrict__ w1b, ushort* __restrict__ w2b) {
  const int NX = T_TOKENS * DIM / 4;
  const int NW1 = NEXP * 2048 * DIM / 4;
  const int NW2 = NEXP * DIM * DFFH / 4;
  const int total = NX + NW1 + NW2;
  for (int i = blockIdx.x * 256 + threadIdx.x; i < total; i += 2048 * 256) {
    float4 v; ushort* dst;
    if (i < NX) { v = x[i]; dst = xb + (size_t)i * 4; }
    else if (i < NX + NW1) { int j = i - NX; v = w1[j]; dst = w1b + (size_t)j * 4; }
    else { int j = i - NX - NW1; v = w2[j]; dst = w2b + (size_t)j * 4; }
    ushort4 o4;
    o4.x = f2bf(v.x); o4.y = f2bf(v.y); o4.z = f2bf(v.z); o4.w = f2bf(v.w);
    *(ushort4*)dst = o4;
  }
}

// ---------------- gating: logits, top-2, renormalized weights ----------------
__global__ __launch_bounds__(256) void gate_kernel(
    const float4* __restrict__ x4, const float4* __restrict__ Wg4,
    const float* __restrict__ bg, int* __restrict__ top2e,
    float2* __restrict__ top2w) {
  __shared__ float4 wgl[NEXP * 256];
  const int tid = threadIdx.x;
  for (int i = tid; i < NEXP * 256; i += 256) wgl[i] = Wg4[i];
  __syncthreads();
  const int wave = tid >> 6, lane = tid & 63;
  const float bgsel = bg[lane & 7];
  const int t0 = (blockIdx.x * 4 + wave) * 16;
  for (int tt = 0; tt < 16; ++tt) {
    const int t = t0 + tt;
    const float4* xr = x4 + (size_t)t * 256;
    float acc[NEXP];
#pragma unroll
    for (int e = 0; e < NEXP; ++e) acc[e] = 0.f;
#pragma unroll
    for (int j = 0; j < 4; ++j) {
      float4 xv = xr[lane + j * 64];
#pragma unroll
      for (int e = 0; e < NEXP; ++e) {
        float4 wv = wgl[e * 256 + lane + j * 64];
        acc[e] += xv.x * wv.x + xv.y * wv.y + xv.z * wv.z + xv.w * wv.w;
      }
    }
#pragma unroll
    for (int e = 0; e < NEXP; ++e) {
      float v = acc[e];
      v += __shfl_xor(v, 1); v += __shfl_xor(v, 2); v += __shfl_xor(v, 4);
      acc[e] = v;
    }
    float v = acc[0];
#pragma unroll
    for (int e = 1; e < NEXP; ++e) v = ((lane & 7) == e) ? acc[e] : v;
    v += __shfl_xor(v, 8); v += __shfl_xor(v, 16); v += __shfl_xor(v, 32);
    v += bgsel;
    float m1 = v;
    m1 = fmaxf(m1, __shfl_xor(m1, 1));
    m1 = fmaxf(m1, __shfl_xor(m1, 2));
    m1 = fmaxf(m1, __shfl_xor(m1, 4));
    unsigned long long mk = __ballot(v == m1);
    int bi = (int)(__ffsll(mk) - 1) & 7;
    float v2 = (((lane & 7) == bi) ? -1e30f : v);
    float m2 = v2;
    m2 = fmaxf(m2, __shfl_xor(m2, 1));
    m2 = fmaxf(m2, __shfl_xor(m2, 2));
    m2 = fmaxf(m2, __shfl_xor(m2, 4));
    mk = __ballot(v2 == m2);
    int si = (int)(__ffsll(mk) - 1) & 7;
    if (lane == 0) {
      float w0 = 1.f / (1.f + __expf(m2 - m1));
      top2e[t] = bi | (si << 8);
      top2w[t] = make_float2(w0, 1.f - w0);
    }
  }
}

// ---------------- routing: counts, padded offsets, per-chunk bases ----------------
__global__ __launch_bounds__(1024) void route_kernel(
    const int* __restrict__ top2e, int* __restrict__ cnt,
    int* __restrict__ off, int* __restrict__ base /*[NCHUNK][NEXP]*/) {
  __shared__ int chunkcnt[NCHUNK][NEXP];
  const int tid = threadIdx.x;
  int c[NEXP];
#pragma unroll
  for (int e = 0; e < NEXP; ++e) c[e] = 0;
  const int4* p = (const int4*)(top2e + tid * 8);
  int4 a = p[0], b = p[1];
  int vals[8] = {a.x, a.y, a.z, a.w, b.x, b.y, b.z, b.w};
#pragma unroll
  for (int k = 0; k < 8; ++k) {
    int e0 = vals[k] & 255, e1 = (vals[k] >> 8) & 255;
#pragma unroll
    for (int e = 0; e < NEXP; ++e) c[e] += (e0 == e) + (e1 == e);
  }
#pragma unroll
  for (int e = 0; e < NEXP; ++e) {
    c[e] += __shfl_xor(c[e], 1);  c[e] += __shfl_xor(c[e], 2);
    c[e] += __shfl_xor(c[e], 4);  c[e] += __shfl_xor(c[e], 8);
    c[e] += __shfl_xor(c[e], 16); c[e] += __shfl_xor(c[e], 32);
  }
  const int wave = tid >> 6, lane = tid & 63;
  if (lane == 0) {
#pragma unroll
    for (int e = 0; e < NEXP; ++e) chunkcnt[wave][e] = c[e];
  }
  __syncthreads();
  if (tid == 0) {
    int o = 0;
    off[0] = 0;
    for (int e = 0; e < NEXP; ++e) {
      int tot = 0;
      for (int w = 0; w < NCHUNK; ++w) tot += chunkcnt[w][e];
      cnt[e] = tot;
      int run = o;
      for (int w = 0; w < NCHUNK; ++w) { base[w * NEXP + e] = run; run += chunkcnt[w][e]; }
      o += (tot + 127) & ~127;
      off[e + 1] = o;
    }
  }
}

// ---------------- scatter tokens into compacted per-expert lists ----------------
__global__ __launch_bounds__(512) void scatter_kernel(
    const int* __restrict__ top2e, const float2* __restrict__ top2w,
    const int* __restrict__ base, int* __restrict__ rows_token,
    float* __restrict__ rows_weight, int2* __restrict__ tok2row) {
  __shared__ int lcnt[NEXP];
  const int tid = threadIdx.x;
  if (tid < NEXP) lcnt[tid] = 0;
  __syncthreads();
  const int b = blockIdx.x;
  const int t = b * 512 + tid;
  int pk = top2e[t];
  float2 w = top2w[t];
  int e0 = pk & 255, e1 = (pk >> 8) & 255;
  int p0 = atomicAdd(&lcnt[e0], 1);
  int p1 = atomicAdd(&lcnt[e1], 1);
  int r0 = base[b * NEXP + e0] + p0;
  int r1 = base[b * NEXP + e1] + p1;
  rows_token[r0] = t; rows_weight[r0] = w.x;
  rows_token[r1] = t; rows_weight[r1] = w.y;
  tok2row[t] = make_int2(r0, r1);
}

// ---------------- expert GEMM 1: h = X@w1e.T, a = silu(gate)*up ----------------
// 2-phase pipelined dbuf; wave grid 2x2 (Wm=64, Wn=32 per gate/up half).
// 1-D grid with XCD grouping: bid = nt*512 + (e*64+mt); siblings sharing an
// A-tile have ids == gidx (mod 512) -> same XCD under round-robin dispatch.
__global__ __launch_bounds__(256) void mlpA_kernel(
    const ushort* __restrict__ xb, const ushort* __restrict__ w1b,
    const int* __restrict__ rows_token, const int* __restrict__ cnt,
    const int* __restrict__ off, ushort* __restrict__ abuf) {
  const int bid = blockIdx.x;
  const int nt = bid >> 9;
  const int gidx = bid & 511;
  const int mt = gidx & 63, e = gidx >> 6;
  const int count = cnt[e];
  if (mt * 128 >= count) return;
  const int base = off[e];

  __shared__ ushort As[2][128 * 64];
  __shared__ ushort Bs[2][2][64 * 64];

  const int tid = threadIdx.x;
  const int wave = tid >> 6, lane = tid & 63;
  const int wm = wave >> 1, wn = wave & 1;
  const int cg = tid & 7;
  const int r7w = (tid >> 3) & 7;          // staged row & 7
  const int cgs = (cg ^ r7w) * 8;          // swizzled source column (elements)

  const ushort* gA[4];
#pragma unroll
  for (int i = 0; i < 4; ++i) {
    int row = i * 32 + (tid >> 3);
    int r = mt * 128 + row;
    int tok = (r < count) ? rows_token[base + r] : 0;
    gA[i] = xb + ((size_t)tok * DIM + cgs);
  }
  const ushort* gBg[2];
  const ushort* gBu[2];
#pragma unroll
  for (int i = 0; i < 2; ++i) {
    int row = i * 32 + (tid >> 3);
    gBg[i] = w1b + ((size_t)(e * 2048 + nt * 64 + row) * DIM + cgs);
    gBu[i] = w1b + ((size_t)(e * 2048 + 1024 + nt * 64 + row) * DIM + cgs);
  }

#define STAGE_A1(b_, k0_)                                             \
  {                                                                   \
    _Pragma("unroll")                                                 \
    for (int i = 0; i < 4; ++i)                                       \
      async16(gA[i] + (k0_), &As[b_][(i * 256 + wave * 64) * 8]);     \
    _Pragma("unroll")                                                 \
    for (int i = 0; i < 2; ++i) {                                     \
      async16(gBg[i] + (k0_), &Bs[b_][0][(i * 256 + wave * 64) * 8]); \
      async16(gBu[i] + (k0_), &Bs[b_][1][(i * 256 + wave * 64) * 8]); \
    }                                                                 \
  }

  const f32x4 zero = {0.f, 0.f, 0.f, 0.f};
  f32x4 accg[4][2], accu[4][2];
#pragma unroll
  for (int m = 0; m < 4; ++m)
#pragma unroll
    for (int n = 0; n < 2; ++n) { accg[m][n] = zero; accu[m][n] = zero; }

  const int xr = (lane & 7) << 3;          // read-side XOR

  STAGE_A1(0, 0);
  __syncthreads();

  for (int t = 0; t < 16; ++t) {
    const int b = t & 1;
    if (t < 15) STAGE_A1(b ^ 1, (t + 1) * 64);
#pragma unroll
    for (int kk = 0; kk < 2; ++kk) {
      const int ko = (kk * 32 + (lane >> 4) * 8) ^ xr;
      bf16x8 af[4];
#pragma unroll
      for (int m = 0; m < 4; ++m)
        af[m] = *(const bf16x8*)&As[b][(wm * 64 + m * 16 + (lane & 15)) * 64 + ko];
#pragma unroll
      for (int n = 0; n < 2; ++n) {
        bf16x8 bgf = *(const bf16x8*)&Bs[b][0][(wn * 32 + n * 16 + (lane & 15)) * 64 + ko];
        bf16x8 buf_ = *(const bf16x8*)&Bs[b][1][(wn * 32 + n * 16 + (lane & 15)) * 64 + ko];
#pragma unroll
        for (int m = 0; m < 4; ++m) {
          accg[m][n] = __builtin_amdgcn_mfma_f32_16x16x32_bf16(af[m], bgf, accg[m][n], 0, 0, 0);
          accu[m][n] = __builtin_amdgcn_mfma_f32_16x16x32_bf16(af[m], buf_, accu[m][n], 0, 0, 0);
        }
      }
    }
    __syncthreads();
  }

  const size_t arow0 = (size_t)(base + mt * 128 + wm * 64);
#pragma unroll
  for (int m = 0; m < 4; ++m)
#pragma unroll
    for (int n = 0; n < 2; ++n)
#pragma unroll
      for (int r = 0; r < 4; ++r) {
        float g = accg[m][n][r], u = accu[m][n][r];
        float a = (g / (1.f + __expf(-g))) * u;   // silu(g)*u
        size_t row = arow0 + m * 16 + (lane >> 4) * 4 + r;
        int col = nt * 64 + wn * 32 + n * 16 + (lane & 15);
        abuf[row * DFFH + col] = f2bf(a);
      }
}

// ---------------- expert GEMM 2: o_partial = A@w2e.T (weighted, non-atomic) ----
// Mirrors mlpA structure: BM=128, BN=64, 48 KB LDS (3 blocks/CU), 2-phase dbuf,
// same XCD grouping. Writes wgt*acc as bf16 to obuf[compacted_row] — no atomics.
__global__ __launch_bounds__(256) void mlpB_kernel(
    const ushort* __restrict__ abuf, const ushort* __restrict__ w2b,
    const float* __restrict__ rows_weight, const int* __restrict__ cnt,
    const int* __restrict__ off, ushort* __restrict__ obuf) {
  const int bid = blockIdx.x;
  const int nt = bid >> 9;
  const int gidx = bid & 511;
  const int mt = gidx & 63, e = gidx >> 6;
  const int count = cnt[e];
  if (mt * 128 >= count) return;
  const int base = off[e];

  __shared__ ushort As[2][128 * 64];
  __shared__ ushort Bs[2][64 * 64];

  const int tid = threadIdx.x;
  const int wave = tid >> 6, lane = tid & 63;
  const int wm = wave >> 1, wn = wave & 1;
  const int cg = tid & 7;
  const int r7w = (tid >> 3) & 7;
  const int cgs = (cg ^ r7w) * 8;

  const ushort* gA[4];
#pragma unroll
  for (int i = 0; i < 4; ++i) {
    int row = i * 32 + (tid >> 3);
    gA[i] = abuf + ((size_t)(base + mt * 128 + row) * DFFH + cgs);
  }
  const ushort* gB[2];
#pragma unroll
  for (int i = 0; i < 2; ++i) {
    int row = i * 32 + (tid >> 3);
    gB[i] = w2b + ((size_t)(e * 1024 + nt * 64 + row) * DFFH + cgs);
  }

#define STAGE_B1(b_, k0_)                                           \
  {                                                                 \
    _Pragma("unroll")                                               \
    for (int i = 0; i < 4; ++i)                                     \
      async16(gA[i] + (k0_), &As[b_][(i * 256 + wave * 64) * 8]);   \
    _Pragma("unroll")                                               \
    for (int i = 0; i < 2; ++i)                                     \
      async16(gB[i] + (k0_), &Bs[b_][(i * 256 + wave * 64) * 8]);   \
  }

  const f32x4 zero = {0.f, 0.f, 0.f, 0.f};
  f32x4 acc[4][2];
#pragma unroll
  for (int m = 0; m < 4; ++m)
#pragma unroll
    for (int n = 0; n < 2; ++n) acc[m][n] = zero;

  const int xr = (lane & 7) << 3;

  STAGE_B1(0, 0);
  __syncthreads();

  for (int t = 0; t < 16; ++t) {
    const int b = t & 1;
    if (t < 15) STAGE_B1(b ^ 1, (t + 1) * 64);
#pragma unroll
    for (int kk = 0; kk < 2; ++kk) {
      const int ko = (kk * 32 + (lane >> 4) * 8) ^ xr;
      bf16x8 af[4];
#pragma unroll
      for (int m = 0; m < 4; ++m)
        af[m] = *(const bf16x8*)&As[b][(wm * 64 + m * 16 + (lane & 15)) * 64 + ko];
#pragma unroll
      for (int n = 0; n < 2; ++n) {
        bf16x8 bf_ = *(const bf16x8*)&Bs[b][(wn * 32 + n * 16 + (lane & 15)) * 64 + ko];
#pragma unroll
        for (int m = 0; m < 4; ++m)
          acc[m][n] = __builtin_amdgcn_mfma_f32_16x16x32_bf16(af[m], bf_, acc[m][n], 0, 0, 0);
      }
    }
    __syncthreads();
  }

#pragma unroll
  for (int m = 0; m < 4; ++m) {
#pragma unroll
    for (int r = 0; r < 4; ++r) {
      int lrow = mt * 128 + wm * 64 + m * 16 + (lane >> 4) * 4 + r;
      if (lrow < count) {
        float wgt = rows_weight[base + lrow];
#pragma unroll
        for (int n = 0; n < 2; ++n) {
          int col = nt * 64 + wn * 32 + n * 16 + (lane & 15);
          obuf[(size_t)(base + lrow) * DIM + col] = f2bf(wgt * acc[m][n][r]);
        }
      }
    }
  }
}

// ---------------- combine: out[t] = obuf[r0] + obuf[r1] ----------------
__global__ __launch_bounds__(256) void combine_kernel(
    const ushort* __restrict__ obuf, const int2* __restrict__ tok2row,
    float* __restrict__ out) {
  const int t = blockIdx.x;
  int2 rr = tok2row[t];
  const ushort4* p0 = (const ushort4*)(obuf + (size_t)rr.x * DIM);
  const ushort4* p1 = (const ushort4*)(obuf + (size_t)rr.y * DIM);
  float4* po = (float4*)(out + (size_t)t * DIM);
  const int c = threadIdx.x;   // 256 threads x 4 elems = 1024
  ushort4 a = p0[c], b = p1[c];
  float4 o;
  o.x = bf2f(a.x) + bf2f(b.x);
  o.y = bf2f(a.y) + bf2f(b.y);
  o.z = bf2f(a.z) + bf2f(b.z);
  o.w = bf2f(a.w) + bf2f(b.w);
  po[c] = o;
}

// ---------------- host ----------------
extern "C" void kernel_launch(void* const* d_in, const int* in_sizes, int n_in,
                              void* d_out, int out_size, void* d_ws, size_t ws_size,
                              hipStream_t stream) {
  const float* x = (const float*)d_in[0];
  const float* Wg = (const float*)d_in[1];
  const float* bg = (const float*)d_in[2];
  const float* w1 = (const float*)d_in[3];
  const float* w2 = (const float*)d_in[4];
  float* out = (float*)d_out;

  char* ws = (char*)d_ws;
  ushort* xb = (ushort*)ws;
  ushort* w1b = xb + (size_t)T_TOKENS * DIM;
  ushort* w2b = w1b + (size_t)NEXP * 2048 * DIM;
  ushort* abuf = w2b + (size_t)NEXP * DIM * DFFH;
  char* p = (char*)(abuf + (size_t)ROWCAP * DFFH);
  int* top2e = (int*)p;            p += T_TOKENS * 4;
  float2* top2w = (float2*)p;      p += T_TOKENS * 8;
  int* rows_token = (int*)p;       p += ROWCAP * 4;
  float* rows_weight = (float*)p;  p += ROWCAP * 4;
  int2* tok2row = (int2*)p;        p += T_TOKENS * 8;
  int* cnt = (int*)p;              p += 32;
  int* off = (int*)p;              p += 64;
  int* base = (int*)p;             p += NCHUNK * NEXP * 4;
  // obuf aliases xb/w1b (both dead after mlpA completes; stream order serializes)
  ushort* obuf = xb;               // ROWCAP * DIM bf16 = 35.7 MB < 50.3 MB (xb+w1b)

  cast_kernel<<<2048, 256, 0, stream>>>((const float4*)x, (const float4*)w1,
                                        (const float4*)w2, xb, w1b, w2b);
  gate_kernel<<<128, 256, 0, stream>>>((const float4*)x, (const float4*)Wg, bg,
                                       top2e, top2w);
  route_kernel<<<1, 1024, 0, stream>>>(top2e, cnt, off, base);
  scatter_kernel<<<NCHUNK, 512, 0, stream>>>(top2e, top2w, base, rows_token,
                                             rows_weight, tok2row);
  mlpA_kernel<<<16 * 512, 256, 0, stream>>>(xb, w1b, rows_token, cnt, off, abuf);
  mlpB_kernel<<<16 * 512, 256, 0, stream>>>(abuf, w2b, rows_weight, cnt, off, obuf);
  combine_kernel<<<T_TOKENS, 256, 0, stream>>>(obuf, tok2row, out);
}

// Round 7
// 244.184 us; speedup vs baseline: 1.2763x; 1.2763x over previous
//
#include <hip/hip_runtime.h>
#include <hip/hip_bf16.h>
#include <cstdint>

#define T_TOKENS 8192
#define DIM 1024
#define NEXP 8
#define DFFH 1024      // DFF/2
#define ROWCAP 17408   // >= 2*T + 8*127, rounded
#define NCHUNK 16      // scatter chunks (512 tokens each)
#define MAXMT 24       // per-expert row-tile capacity (cnt<=3072; mean 2048, sigma~42)

typedef __attribute__((ext_vector_type(8))) short bf16x8;
typedef __attribute__((ext_vector_type(4))) float f32x4;

__device__ __forceinline__ ushort f2bf(float f) {
  uint32_t u = __float_as_uint(f);
  uint32_t r = (u + 0x7fffu + ((u >> 16) & 1u)) >> 16;
  return (ushort)r;
}
__device__ __forceinline__ float bf2f(ushort u) {
  return __uint_as_float(((uint32_t)u) << 16);
}

__device__ __forceinline__ void async16(const void* g, const void* l) {
  __builtin_amdgcn_global_load_lds(
      (const __attribute__((address_space(1))) void*)(uintptr_t)g,
      (__attribute__((address_space(3))) void*)(uintptr_t)l, 16, 0, 0);
}

// ---------------- cast fp32 -> bf16 for w1, w2 (x done in gate) ----------------
__global__ __launch_bounds__(256) void cast_kernel(
    const float4* __restrict__ w1, const float4* __restrict__ w2,
    ushort* __restrict__ w1b, ushort* __restrict__ w2b) {
  const int NW1 = NEXP * 2048 * DIM / 4;
  const int NW2 = NEXP * DIM * DFFH / 4;
  const int total = NW1 + NW2;
  for (int i = blockIdx.x * 256 + threadIdx.x; i < total; i += 2048 * 256) {
    float4 v; ushort* dst;
    if (i < NW1) { v = w1[i]; dst = w1b + (size_t)i * 4; }
    else { int j = i - NW1; v = w2[j]; dst = w2b + (size_t)j * 4; }
    ushort4 o4;
    o4.x = f2bf(v.x); o4.y = f2bf(v.y); o4.z = f2bf(v.z); o4.w = f2bf(v.w);
    *(ushort4*)dst = o4;
  }
}

// ---------------- gating: logits, top-2 weights; also casts x -> xb ----------------
__global__ __launch_bounds__(256) void gate_kernel(
    const float4* __restrict__ x4, const float4* __restrict__ Wg4,
    const float* __restrict__ bg, int* __restrict__ top2e,
    float2* __restrict__ top2w, ushort* __restrict__ xb) {
  __shared__ float4 wgl[NEXP * 256];
  const int tid = threadIdx.x;
  for (int i = tid; i < NEXP * 256; i += 256) wgl[i] = Wg4[i];
  __syncthreads();
  const int wave = tid >> 6, lane = tid & 63;
  const float bgsel = bg[lane & 7];
  const int t0 = (blockIdx.x * 4 + wave) * 16;
  for (int tt = 0; tt < 16; ++tt) {
    const int t = t0 + tt;
    const float4* xr = x4 + (size_t)t * 256;
    ushort4* xw = (ushort4*)(xb + (size_t)t * DIM);
    float acc[NEXP];
#pragma unroll
    for (int e = 0; e < NEXP; ++e) acc[e] = 0.f;
#pragma unroll
    for (int j = 0; j < 4; ++j) {
      float4 xv = xr[lane + j * 64];
      ushort4 o4;
      o4.x = f2bf(xv.x); o4.y = f2bf(xv.y); o4.z = f2bf(xv.z); o4.w = f2bf(xv.w);
      xw[lane + j * 64] = o4;
#pragma unroll
      for (int e = 0; e < NEXP; ++e) {
        float4 wv = wgl[e * 256 + lane + j * 64];
        acc[e] += xv.x * wv.x + xv.y * wv.y + xv.z * wv.z + xv.w * wv.w;
      }
    }
#pragma unroll
    for (int e = 0; e < NEXP; ++e) {
      float v = acc[e];
      v += __shfl_xor(v, 1); v += __shfl_xor(v, 2); v += __shfl_xor(v, 4);
      acc[e] = v;
    }
    float v = acc[0];
#pragma unroll
    for (int e = 1; e < NEXP; ++e) v = ((lane & 7) == e) ? acc[e] : v;
    v += __shfl_xor(v, 8); v += __shfl_xor(v, 16); v += __shfl_xor(v, 32);
    v += bgsel;
    float m1 = v;
    m1 = fmaxf(m1, __shfl_xor(m1, 1));
    m1 = fmaxf(m1, __shfl_xor(m1, 2));
    m1 = fmaxf(m1, __shfl_xor(m1, 4));
    unsigned long long mk = __ballot(v == m1);
    int bi = (int)(__ffsll(mk) - 1) & 7;
    float v2 = (((lane & 7) == bi) ? -1e30f : v);
    float m2 = v2;
    m2 = fmaxf(m2, __shfl_xor(m2, 1));
    m2 = fmaxf(m2, __shfl_xor(m2, 2));
    m2 = fmaxf(m2, __shfl_xor(m2, 4));
    mk = __ballot(v2 == m2);
    int si = (int)(__ffsll(mk) - 1) & 7;
    if (lane == 0) {
      float w0 = 1.f / (1.f + __expf(m2 - m1));
      top2e[t] = bi | (si << 8);
      top2w[t] = make_float2(w0, 1.f - w0);
    }
  }
}

// ---------------- routing: counts, padded offsets, per-chunk bases ----------------
__global__ __launch_bounds__(1024) void route_kernel(
    const int* __restrict__ top2e, int* __restrict__ cnt,
    int* __restrict__ off, int* __restrict__ base /*[NCHUNK][NEXP]*/) {
  __shared__ int chunkcnt[NCHUNK][NEXP];
  const int tid = threadIdx.x;
  int c[NEXP];
#pragma unroll
  for (int e = 0; e < NEXP; ++e) c[e] = 0;
  const int4* p = (const int4*)(top2e + tid * 8);
  int4 a = p[0], b = p[1];
  int vals[8] = {a.x, a.y, a.z, a.w, b.x, b.y, b.z, b.w};
#pragma unroll
  for (int k = 0; k < 8; ++k) {
    int e0 = vals[k] & 255, e1 = (vals[k] >> 8) & 255;
#pragma unroll
    for (int e = 0; e < NEXP; ++e) c[e] += (e0 == e) + (e1 == e);
  }
#pragma unroll
  for (int e = 0; e < NEXP; ++e) {
    c[e] += __shfl_xor(c[e], 1);  c[e] += __shfl_xor(c[e], 2);
    c[e] += __shfl_xor(c[e], 4);  c[e] += __shfl_xor(c[e], 8);
    c[e] += __shfl_xor(c[e], 16); c[e] += __shfl_xor(c[e], 32);
  }
  const int wave = tid >> 6, lane = tid & 63;
  if (lane == 0) {
#pragma unroll
    for (int e = 0; e < NEXP; ++e) chunkcnt[wave][e] = c[e];
  }
  __syncthreads();
  if (tid == 0) {
    int o = 0;
    off[0] = 0;
    for (int e = 0; e < NEXP; ++e) {
      int tot = 0;
      for (int w = 0; w < NCHUNK; ++w) tot += chunkcnt[w][e];
      cnt[e] = tot;
      int run = o;
      for (int w = 0; w < NCHUNK; ++w) { base[w * NEXP + e] = run; run += chunkcnt[w][e]; }
      o += (tot + 127) & ~127;
      off[e + 1] = o;
    }
  }
}

// ---------------- scatter tokens into compacted per-expert lists ----------------
__global__ __launch_bounds__(512) void scatter_kernel(
    const int* __restrict__ top2e, const float2* __restrict__ top2w,
    const int* __restrict__ base, int* __restrict__ rows_token,
    float* __restrict__ rows_weight, int2* __restrict__ tok2row) {
  __shared__ int lcnt[NEXP];
  const int tid = threadIdx.x;
  if (tid < NEXP) lcnt[tid] = 0;
  __syncthreads();
  const int b = blockIdx.x;
  const int t = b * 512 + tid;
  int pk = top2e[t];
  float2 w = top2w[t];
  int e0 = pk & 255, e1 = (pk >> 8) & 255;
  int p0 = atomicAdd(&lcnt[e0], 1);
  int p1 = atomicAdd(&lcnt[e1], 1);
  int r0 = base[b * NEXP + e0] + p0;
  int r1 = base[b * NEXP + e1] + p1;
  rows_token[r0] = t; rows_weight[r0] = w.x;
  rows_token[r1] = t; rows_weight[r1] = w.y;
  tok2row[t] = make_int2(r0, r1);
}

// ---------------- expert GEMM 1: h = X@w1e.T, a = silu(gate)*up ----------------
// Expert-pinned XCD mapping: e = bid%8 (HW round-robin -> all expert-e blocks
// on XCD e); pos=bid>>3: mt=pos>>4, nt=pos&15 -> the 16 nt-siblings of one
// A-tile are consecutive on one XCD (co-resident; A from L2). Per-XCD weight
// stream = w1[e] (4MB ~ L2) stays resident. 2-phase dbuf + T2 swizzle kept.
__global__ __launch_bounds__(256) void mlpA_kernel(
    const ushort* __restrict__ xb, const ushort* __restrict__ w1b,
    const int* __restrict__ rows_token, const int* __restrict__ cnt,
    const int* __restrict__ off, ushort* __restrict__ abuf) {
  const int bid = blockIdx.x;
  const int e = bid & 7;
  const int pos = bid >> 3;
  const int mt = pos >> 4, nt = pos & 15;
  const int count = cnt[e];
  if (mt * 128 >= count) return;
  const int base = off[e];

  __shared__ ushort As[2][128 * 64];
  __shared__ ushort Bs[2][2][64 * 64];

  const int tid = threadIdx.x;
  const int wave = tid >> 6, lane = tid & 63;
  const int wm = wave >> 1, wn = wave & 1;
  const int cg = tid & 7;
  const int r7w = (tid >> 3) & 7;          // staged row & 7
  const int cgs = (cg ^ r7w) * 8;          // swizzled source column (elements)

  const ushort* gA[4];
#pragma unroll
  for (int i = 0; i < 4; ++i) {
    int row = i * 32 + (tid >> 3);
    int r = mt * 128 + row;
    int tok = (r < count) ? rows_token[base + r] : 0;
    gA[i] = xb + ((size_t)tok * DIM + cgs);
  }
  const ushort* gBg[2];
  const ushort* gBu[2];
#pragma unroll
  for (int i = 0; i < 2; ++i) {
    int row = i * 32 + (tid >> 3);
    gBg[i] = w1b + ((size_t)(e * 2048 + nt * 64 + row) * DIM + cgs);
    gBu[i] = w1b + ((size_t)(e * 2048 + 1024 + nt * 64 + row) * DIM + cgs);
  }

#define STAGE_A1(b_, k0_)                                             \
  {                                                                   \
    _Pragma("unroll")                                                 \
    for (int i = 0; i < 4; ++i)                                       \
      async16(gA[i] + (k0_), &As[b_][(i * 256 + wave * 64) * 8]);     \
    _Pragma("unroll")                                                 \
    for (int i = 0; i < 2; ++i) {                                     \
      async16(gBg[i] + (k0_), &Bs[b_][0][(i * 256 + wave * 64) * 8]); \
      async16(gBu[i] + (k0_), &Bs[b_][1][(i * 256 + wave * 64) * 8]); \
    }                                                                 \
  }

  const f32x4 zero = {0.f, 0.f, 0.f, 0.f};
  f32x4 accg[4][2], accu[4][2];
#pragma unroll
  for (int m = 0; m < 4; ++m)
#pragma unroll
    for (int n = 0; n < 2; ++n) { accg[m][n] = zero; accu[m][n] = zero; }

  const int xr = (lane & 7) << 3;          // read-side XOR

  STAGE_A1(0, 0);
  __syncthreads();

  for (int t = 0; t < 16; ++t) {
    const int b = t & 1;
    if (t < 15) STAGE_A1(b ^ 1, (t + 1) * 64);
#pragma unroll
    for (int kk = 0; kk < 2; ++kk) {
      const int ko = (kk * 32 + (lane >> 4) * 8) ^ xr;
      bf16x8 af[4];
#pragma unroll
      for (int m = 0; m < 4; ++m)
        af[m] = *(const bf16x8*)&As[b][(wm * 64 + m * 16 + (lane & 15)) * 64 + ko];
#pragma unroll
      for (int n = 0; n < 2; ++n) {
        bf16x8 bgf = *(const bf16x8*)&Bs[b][0][(wn * 32 + n * 16 + (lane & 15)) * 64 + ko];
        bf16x8 buf_ = *(const bf16x8*)&Bs[b][1][(wn * 32 + n * 16 + (lane & 15)) * 64 + ko];
#pragma unroll
        for (int m = 0; m < 4; ++m) {
          accg[m][n] = __builtin_amdgcn_mfma_f32_16x16x32_bf16(af[m], bgf, accg[m][n], 0, 0, 0);
          accu[m][n] = __builtin_amdgcn_mfma_f32_16x16x32_bf16(af[m], buf_, accu[m][n], 0, 0, 0);
        }
      }
    }
    __syncthreads();
  }

  const size_t arow0 = (size_t)(base + mt * 128 + wm * 64);
#pragma unroll
  for (int m = 0; m < 4; ++m)
#pragma unroll
    for (int n = 0; n < 2; ++n)
#pragma unroll
      for (int r = 0; r < 4; ++r) {
        float g = accg[m][n][r], u = accu[m][n][r];
        float a = (g / (1.f + __expf(-g))) * u;   // silu(g)*u
        size_t row = arow0 + m * 16 + (lane >> 4) * 4 + r;
        int col = nt * 64 + wn * 32 + n * 16 + (lane & 15);
        abuf[row * DFFH + col] = f2bf(a);
      }
}

// ---------------- expert GEMM 2: o_partial = A@w2e.T (weighted, non-atomic) ----
// Same expert-pinned XCD mapping; per-XCD streams abuf[e] (4MB) + w2[e] (2MB).
__global__ __launch_bounds__(256) void mlpB_kernel(
    const ushort* __restrict__ abuf, const ushort* __restrict__ w2b,
    const float* __restrict__ rows_weight, const int* __restrict__ cnt,
    const int* __restrict__ off, ushort* __restrict__ obuf) {
  const int bid = blockIdx.x;
  const int e = bid & 7;
  const int pos = bid >> 3;
  const int mt = pos >> 4, nt = pos & 15;
  const int count = cnt[e];
  if (mt * 128 >= count) return;
  const int base = off[e];

  __shared__ ushort As[2][128 * 64];
  __shared__ ushort Bs[2][64 * 64];

  const int tid = threadIdx.x;
  const int wave = tid >> 6, lane = tid & 63;
  const int wm = wave >> 1, wn = wave & 1;
  const int cg = tid & 7;
  const int r7w = (tid >> 3) & 7;
  const int cgs = (cg ^ r7w) * 8;

  const ushort* gA[4];
#pragma unroll
  for (int i = 0; i < 4; ++i) {
    int row = i * 32 + (tid >> 3);
    gA[i] = abuf + ((size_t)(base + mt * 128 + row) * DFFH + cgs);
  }
  const ushort* gB[2];
#pragma unroll
  for (int i = 0; i < 2; ++i) {
    int row = i * 32 + (tid >> 3);
    gB[i] = w2b + ((size_t)(e * 1024 + nt * 64 + row) * DFFH + cgs);
  }

#define STAGE_B1(b_, k0_)                                           \
  {                                                                 \
    _Pragma("unroll")                                               \
    for (int i = 0; i < 4; ++i)                                     \
      async16(gA[i] + (k0_), &As[b_][(i * 256 + wave * 64) * 8]);   \
    _Pragma("unroll")                                               \
    for (int i = 0; i < 2; ++i)                                     \
      async16(gB[i] + (k0_), &Bs[b_][(i * 256 + wave * 64) * 8]);   \
  }

  const f32x4 zero = {0.f, 0.f, 0.f, 0.f};
  f32x4 acc[4][2];
#pragma unroll
  for (int m = 0; m < 4; ++m)
#pragma unroll
    for (int n = 0; n < 2; ++n) acc[m][n] = zero;

  const int xr = (lane & 7) << 3;

  STAGE_B1(0, 0);
  __syncthreads();

  for (int t = 0; t < 16; ++t) {
    const int b = t & 1;
    if (t < 15) STAGE_B1(b ^ 1, (t + 1) * 64);
#pragma unroll
    for (int kk = 0; kk < 2; ++kk) {
      const int ko = (kk * 32 + (lane >> 4) * 8) ^ xr;
      bf16x8 af[4];
#pragma unroll
      for (int m = 0; m < 4; ++m)
        af[m] = *(const bf16x8*)&As[b][(wm * 64 + m * 16 + (lane & 15)) * 64 + ko];
#pragma unroll
      for (int n = 0; n < 2; ++n) {
        bf16x8 bf_ = *(const bf16x8*)&Bs[b][(wn * 32 + n * 16 + (lane & 15)) * 64 + ko];
#pragma unroll
        for (int m = 0; m < 4; ++m)
          acc[m][n] = __builtin_amdgcn_mfma_f32_16x16x32_bf16(af[m], bf_, acc[m][n], 0, 0, 0);
      }
    }
    __syncthreads();
  }

#pragma unroll
  for (int m = 0; m < 4; ++m) {
#pragma unroll
    for (int r = 0; r < 4; ++r) {
      int lrow = mt * 128 + wm * 64 + m * 16 + (lane >> 4) * 4 + r;
      if (lrow < count) {
        float wgt = rows_weight[base + lrow];
#pragma unroll
        for (int n = 0; n < 2; ++n) {
          int col = nt * 64 + wn * 32 + n * 16 + (lane & 15);
          obuf[(size_t)(base + lrow) * DIM + col] = f2bf(wgt * acc[m][n][r]);
        }
      }
    }
  }
}

// ---------------- combine: out[t] = obuf[r0] + obuf[r1] ----------------
__global__ __launch_bounds__(256) void combine_kernel(
    const ushort* __restrict__ obuf, const int2* __restrict__ tok2row,
    float* __restrict__ out) {
  const int t = blockIdx.x;
  int2 rr = tok2row[t];
  const ushort4* p0 = (const ushort4*)(obuf + (size_t)rr.x * DIM);
  const ushort4* p1 = (const ushort4*)(obuf + (size_t)rr.y * DIM);
  float4* po = (float4*)(out + (size_t)t * DIM);
  const int c = threadIdx.x;   // 256 threads x 4 elems = 1024
  ushort4 a = p0[c], b = p1[c];
  float4 o;
  o.x = bf2f(a.x) + bf2f(b.x);
  o.y = bf2f(a.y) + bf2f(b.y);
  o.z = bf2f(a.z) + bf2f(b.z);
  o.w = bf2f(a.w) + bf2f(b.w);
  po[c] = o;
}

// ---------------- host ----------------
extern "C" void kernel_launch(void* const* d_in, const int* in_sizes, int n_in,
                              void* d_out, int out_size, void* d_ws, size_t ws_size,
                              hipStream_t stream) {
  const float* x = (const float*)d_in[0];
  const float* Wg = (const float*)d_in[1];
  const float* bg = (const float*)d_in[2];
  const float* w1 = (const float*)d_in[3];
  const float* w2 = (const float*)d_in[4];
  float* out = (float*)d_out;

  char* ws = (char*)d_ws;
  ushort* xb = (ushort*)ws;
  ushort* w1b = xb + (size_t)T_TOKENS * DIM;
  ushort* w2b = w1b + (size_t)NEXP * 2048 * DIM;
  ushort* abuf = w2b + (size_t)NEXP * DIM * DFFH;
  char* p = (char*)(abuf + (size_t)ROWCAP * DFFH);
  int* top2e = (int*)p;            p += T_TOKENS * 4;
  float2* top2w = (float2*)p;      p += T_TOKENS * 8;
  int* rows_token = (int*)p;       p += ROWCAP * 4;
  float* rows_weight = (float*)p;  p += ROWCAP * 4;
  int2* tok2row = (int2*)p;        p += T_TOKENS * 8;
  int* cnt = (int*)p;              p += 32;
  int* off = (int*)p;              p += 64;
  int* base = (int*)p;             p += NCHUNK * NEXP * 4;
  // obuf aliases xb/w1b (both dead after mlpA completes; stream order serializes)
  ushort* obuf = xb;               // ROWCAP * DIM bf16 = 35.7 MB < 50.3 MB (xb+w1b)

  cast_kernel<<<2048, 256, 0, stream>>>((const float4*)w1, (const float4*)w2,
                                        w1b, w2b);
  gate_kernel<<<128, 256, 0, stream>>>((const float4*)x, (const float4*)Wg, bg,
                                       top2e, top2w, xb);
  route_kernel<<<1, 1024, 0, stream>>>(top2e, cnt, off, base);
  scatter_kernel<<<NCHUNK, 512, 0, stream>>>(top2e, top2w, base, rows_token,
                                             rows_weight, tok2row);
  mlpA_kernel<<<8 * MAXMT * 16, 256, 0, stream>>>(xb, w1b, rows_token, cnt, off, abuf);
  mlpB_kernel<<<8 * MAXMT * 16, 256, 0, stream>>>(abuf, w2b, rows_weight, cnt, off, obuf);
  combine_kernel<<<T_TOKENS, 256, 0, stream>>>(obuf, tok2row, out);
}